// Round 4
// baseline (561.278 us; speedup 1.0000x reference)
//
#include <hip/hip_runtime.h>
#include <hip/hip_bf16.h>
#include <stdint.h>

#define T_ 2
#define H_ 384
#define W_ 384
#define C_ 128
#define HN_ 48
#define WN_ 48
#define NWIN_ (T_*HN_*WN_)
#define SCALE_ 0.17677669529663687f

typedef float f32x4 __attribute__((ext_vector_type(4)));
typedef float f32x2 __attribute__((ext_vector_type(2)));
typedef short bf16x8 __attribute__((ext_vector_type(8)));

// ---- workspace ----
#define WS_WFRAG 0        // 4 mats x [nt8][ks][lane][8] bf16 = 131072 B
#define WS_BIASX 131072   // [he][n][c16][m2] f32 = 65536 B

// ---- LDS: 48 KB, packed rows + XOR swizzle ----
// tmp[64 px][256B]  (overlay: vt[128 d][128B])
// q  [64 n][256B]   (overlay: P rows 0-127 [128B], O[64][256B])
// k  [64 n][256B]   (overlay: P rows 128-255 [128B])
#define TMP_OFF 0
#define Q_OFF   16384
#define K_OFF   32768
#define SMEM_SZ 49152

__device__ __forceinline__ unsigned int pkbf(float a, float b){
  __hip_bfloat162 h = __float22bfloat162_rn(make_float2(a, b));
  union { __hip_bfloat162 h; unsigned int u; } c; c.h = h; return c.u;
}
__device__ __forceinline__ unsigned short f2bf(float f){
  union{float f;unsigned int i;}x; x.f=f;
  unsigned int r = x.i + 0x7fffu + ((x.i>>16)&1u);
  return (unsigned short)(r>>16);
}
__device__ __forceinline__ int swz256(int row, int b){ return row*256 + (b ^ ((row & 7) << 4)); }
__device__ __forceinline__ int swz128(int row, int b){ return row*128 + (b ^ ((row & 7) << 4)); }

// ---------- prep: weights -> bf16 fragment order; rpb -> expanded fragment bias ----------
__global__ __launch_bounds__(256)
void prep_kernel(const float* __restrict__ qpw, const float* __restrict__ kpw,
                 const float* __restrict__ vpw, const float* __restrict__ pjw,
                 const float* __restrict__ rpb, ushort* __restrict__ wfrag,
                 float* __restrict__ biasx)
{
  const int idx = blockIdx.x*256 + threadIdx.x;
  if (idx < 8192) {
    const int mat = idx >> 11, rem = idx & 2047;
    const int nt8 = rem >> 8, ks = (rem >> 6) & 3, lane = rem & 63;
    const int c16 = lane & 15, g = lane >> 4;
    const float* Ws[4] = {qpw, kpw, vpw, pjw};
    const float* src = Ws[mat] + (nt8*16 + c16)*128 + ks*32 + g*8;
    ushort* dst = wfrag + idx*8;
    #pragma unroll
    for (int e = 0; e < 8; ++e) dst[e] = f2bf(src[e]);
  } else if (idx < 8192 + 16384) {
    const int i2 = idx - 8192;
    const int he = i2 >> 12, n = (i2 >> 6) & 63, m = i2 & 63;
    const int ny = n >> 3, nx = n & 7, my = m >> 3, mx = m & 7;
    biasx[((he*64 + n)*16 + (m & 15))*4 + (m >> 4)] =
        rpb[((ny - my + 7)*15 + (nx - mx + 7))*4 + he];
  }
}

// ---------- main ----------
__global__ __launch_bounds__(512, 6)
void winattn_mfma3(const float* __restrict__ vid,
                   const float* __restrict__ qdw, const float* __restrict__ qdwb,
                   const float* __restrict__ kdw, const float* __restrict__ kdwb,
                   const float* __restrict__ vdw, const float* __restrict__ vdwb,
                   const float* __restrict__ qpwb, const float* __restrict__ kpwb,
                   const float* __restrict__ vpwb, const float* __restrict__ pjb,
                   const ushort* __restrict__ wfrag, const float* __restrict__ biasx,
                   float* __restrict__ out)
{
  __shared__ __attribute__((aligned(16))) char smem[SMEM_SZ];
  char* tmpb = smem + TMP_OFF;   // tmp (256B rows) / vt (128B rows)
  char* qb   = smem + Q_OFF;     // q (256B rows) / P[0:128) / O
  char* kb   = smem + K_OFF;     // k (256B rows) / P[128:256)

  const int tid  = threadIdx.x;
  const int w    = tid >> 6;
  const int lane = tid & 63;
  const int g    = lane >> 4;
  const int c16  = lane & 15;

  // XCD-aware bijective swizzle (4608 % 8 == 0): consecutive windows share an XCD
  const int wid = (blockIdx.x & 7) * (NWIN_ / 8) + (blockIdx.x >> 3);
  const int t  = wid / (HN_*WN_);
  const int hw = wid % (HN_*WN_);
  const int hn = hw / WN_, wn = hw % WN_;
  const int h0 = hn*8, w0 = wn*8;

  // ---- input halo -> registers (wave = row y, lane = channel pair) ----
  const int y  = w;
  const int c0 = 2*lane;
  f32x2 xv[3][10];
  #pragma unroll
  for (int dy = 0; dy < 3; ++dy){
    const int hh = h0 + y - 1 + dy;
    const bool rv = (unsigned)hh < (unsigned)H_;
    #pragma unroll
    for (int xc = 0; xc < 10; ++xc){
      const int ww = w0 - 1 + xc;
      f32x2 v = {0.f, 0.f};
      if (rv && (unsigned)ww < (unsigned)W_){
        const float2 l = *reinterpret_cast<const float2*>(&vid[(((long)t*H_ + hh)*W_ + ww)*C_ + c0]);
        v[0] = l.x; v[1] = l.y;
      }
      xv[dy][xc] = v;
    }
  }

  const float* DW[3]  = {qdw, kdw, vdw};
  const float* DWB[3] = {qdwb, kdwb, vdwb};
  const float* PWB[3] = {qpwb, kpwb, vpwb};

  const int mt  = w & 3;
  const int ntb = (w >> 2) * 4;
  const int n0  = mt*16 + g*4;

  #pragma unroll
  for (int p = 0; p < 3; ++p) {
    // ---- depthwise 3x3 + bias + relu (packed f32x2) -> tmp ----
    {
      const float* dwp = DW[p] + (long)c0*9;
      f32x2 wgt[9];
      #pragma unroll
      for (int k2 = 0; k2 < 9; ++k2){ wgt[k2] = (f32x2){dwp[k2], dwp[9+k2]}; }
      const float2 bb = *reinterpret_cast<const float2*>(&DWB[p][c0]);
      #pragma unroll
      for (int px = 0; px < 8; ++px){
        f32x2 a = {bb.x, bb.y};
        #pragma unroll
        for (int dy = 0; dy < 3; ++dy)
          #pragma unroll
          for (int dx = 0; dx < 3; ++dx)
            a += xv[dy][px+dx] * wgt[dy*3+dx];
        const float ax = fmaxf(a[0], 0.f), ay = fmaxf(a[1], 0.f);
        *reinterpret_cast<unsigned int*>(tmpb + swz256(y*8+px, 4*lane)) = pkbf(ax, ay);
      }
    }
    __syncthreads();
    // ---- pointwise GEMM: Y[64,128] = X @ W^T (B-frags from L2) ----
    f32x4 acc[4];
    #pragma unroll
    for (int nt = 0; nt < 4; ++nt) acc[nt] = (f32x4){0.f,0.f,0.f,0.f};
    {
      const ushort* wp = wfrag + p*16384;
      #pragma unroll
      for (int ks = 0; ks < 4; ++ks){
        const bf16x8 af = *reinterpret_cast<const bf16x8*>(tmpb + swz256(mt*16+c16, ks*64 + g*16));
        #pragma unroll
        for (int nt = 0; nt < 4; ++nt){
          const bf16x8 bf = *reinterpret_cast<const bf16x8*>(&wp[(((ntb+nt)*4 + ks)*64 + lane)*8]);
          acc[nt] = __builtin_amdgcn_mfma_f32_16x16x32_bf16(af, bf, acc[nt], 0, 0, 0);
        }
      }
    }
    if (p < 2) {   // Q (scaled) / K epilogue -> q/k region
      const float scl = (p == 0) ? SCALE_ : 1.0f;
      char* dst = (p == 0) ? qb : kb;
      #pragma unroll
      for (int nt = 0; nt < 4; ++nt){
        const int co = (ntb+nt)*16 + c16;
        const float bias = PWB[p][co];
        const unsigned int u01 = pkbf((acc[nt][0]+bias)*scl, (acc[nt][1]+bias)*scl);
        const unsigned int u23 = pkbf((acc[nt][2]+bias)*scl, (acc[nt][3]+bias)*scl);
        *reinterpret_cast<ushort*>(dst + swz256(n0+0, 2*co)) = (ushort)u01;
        *reinterpret_cast<ushort*>(dst + swz256(n0+1, 2*co)) = (ushort)(u01 >> 16);
        *reinterpret_cast<ushort*>(dst + swz256(n0+2, 2*co)) = (ushort)u23;
        *reinterpret_cast<ushort*>(dst + swz256(n0+3, 2*co)) = (ushort)(u23 >> 16);
      }
      __syncthreads();   // tmp reads done -> next p may overwrite tmp
    } else {
      __syncthreads();   // (C) all tmp reads done -> safe to overlay V^T onto tmp
      #pragma unroll
      for (int nt = 0; nt < 4; ++nt){   // V^T rows d=co, cols n contiguous: one b64 store
        const int co = (ntb+nt)*16 + c16;
        const float bias = PWB[2][co];
        uint2 pk2;
        pk2.x = pkbf(acc[0*0+nt][0]+bias, acc[nt][1]+bias);
        pk2.y = pkbf(acc[nt][2]+bias, acc[nt][3]+bias);
        *reinterpret_cast<uint2*>(tmpb + swz128(co, 2*n0)) = pk2;
      }
    }
  }

  // ---- attention: wave (he, half) owns 32 query rows of head he ----
  const int he = w >> 1, half = w & 1;
  float pe[2][4][4];
  float inv2[2][4];
  {
    f32x4 S[2][4];
    #pragma unroll
    for (int mi = 0; mi < 2; ++mi){
      const bf16x8 qf = *reinterpret_cast<const bf16x8*>(qb + swz256((half*2+mi)*16 + c16, he*64 + g*16));
      #pragma unroll
      for (int m2 = 0; m2 < 4; ++m2){
        const bf16x8 kf = *reinterpret_cast<const bf16x8*>(kb + swz256(m2*16 + c16, he*64 + g*16));
        const f32x4 z = {0.f,0.f,0.f,0.f};
        S[mi][m2] = __builtin_amdgcn_mfma_f32_16x16x32_bf16(qf, kf, z, 0, 0, 0);
      }
    }
    #pragma unroll
    for (int mi = 0; mi < 2; ++mi){
      #pragma unroll
      for (int r = 0; r < 4; ++r){
        const int n = (half*2+mi)*16 + g*4 + r;
        const float4 bx = *reinterpret_cast<const float4*>(&biasx[((he*64+n)*16 + c16)*4]);
        float v0 = S[mi][0][r]+bx.x, v1 = S[mi][1][r]+bx.y;
        float v2 = S[mi][2][r]+bx.z, v3 = S[mi][3][r]+bx.w;
        float mx = fmaxf(fmaxf(v0,v1), fmaxf(v2,v3));
        mx = fmaxf(mx, __shfl_xor(mx, 1));
        mx = fmaxf(mx, __shfl_xor(mx, 2));
        mx = fmaxf(mx, __shfl_xor(mx, 4));
        mx = fmaxf(mx, __shfl_xor(mx, 8));
        const float e0 = __expf(v0-mx), e1 = __expf(v1-mx);
        const float e2 = __expf(v2-mx), e3 = __expf(v3-mx);
        float ls = e0+e1+e2+e3;
        ls += __shfl_xor(ls, 1);
        ls += __shfl_xor(ls, 2);
        ls += __shfl_xor(ls, 4);
        ls += __shfl_xor(ls, 8);
        inv2[mi][r] = 1.0f / ls;          // defer normalization to PV epilogue
        pe[mi][r][0]=e0; pe[mi][r][1]=e1; pe[mi][r][2]=e2; pe[mi][r][3]=e3;
      }
    }
  }
  __syncthreads();   // (D) V^T writes done; all q/k reads done
  // ---- P (unnormalized, bf16) -> overlay q+k region, rows rr=he*64+n ----
  #pragma unroll
  for (int mi = 0; mi < 2; ++mi)
    #pragma unroll
    for (int r = 0; r < 4; ++r){
      const int rr = he*64 + (half*2+mi)*16 + g*4 + r;
      const unsigned int u01 = pkbf(pe[mi][r][0], pe[mi][r][1]);
      const unsigned int u23 = pkbf(pe[mi][r][2], pe[mi][r][3]);
      *reinterpret_cast<ushort*>(qb + swz128(rr,  0 + 2*c16)) = (ushort)u01;
      *reinterpret_cast<ushort*>(qb + swz128(rr, 32 + 2*c16)) = (ushort)(u01 >> 16);
      *reinterpret_cast<ushort*>(qb + swz128(rr, 64 + 2*c16)) = (ushort)u23;
      *reinterpret_cast<ushort*>(qb + swz128(rr, 96 + 2*c16)) = (ushort)(u23 >> 16);
    }
  __syncthreads();   // (E)
  // ---- PV: O = P @ V (A=P from q+k overlay, B=V^T from tmp overlay) ----
  f32x4 oacc[2][2];
  #pragma unroll
  for (int mi = 0; mi < 2; ++mi)
    #pragma unroll
    for (int nt = 0; nt < 2; ++nt) oacc[mi][nt] = (f32x4){0.f,0.f,0.f,0.f};
  #pragma unroll
  for (int ks = 0; ks < 2; ++ks){
    #pragma unroll
    for (int nt = 0; nt < 2; ++nt){
      const bf16x8 vf = *reinterpret_cast<const bf16x8*>(tmpb + swz128(he*32+nt*16+c16, ks*64 + g*16));
      #pragma unroll
      for (int mi = 0; mi < 2; ++mi){
        const bf16x8 pf = *reinterpret_cast<const bf16x8*>(qb + swz128(he*64+(half*2+mi)*16+c16, ks*64 + g*16));
        oacc[mi][nt] = __builtin_amdgcn_mfma_f32_16x16x32_bf16(pf, vf, oacc[mi][nt], 0, 0, 0);
      }
    }
  }
  __syncthreads();   // (F) P reads done -> O may overwrite q region
  #pragma unroll
  for (int mi = 0; mi < 2; ++mi)
    #pragma unroll
    for (int nt = 0; nt < 2; ++nt){
      const int col = he*32 + nt*16 + c16;
      const int nb = (half*2+mi)*16 + g*4;
      const unsigned int u01 = pkbf(oacc[mi][nt][0]*inv2[mi][0], oacc[mi][nt][1]*inv2[mi][1]);
      const unsigned int u23 = pkbf(oacc[mi][nt][2]*inv2[mi][2], oacc[mi][nt][3]*inv2[mi][3]);
      *reinterpret_cast<ushort*>(qb + swz256(nb+0, 2*col)) = (ushort)u01;
      *reinterpret_cast<ushort*>(qb + swz256(nb+1, 2*col)) = (ushort)(u01 >> 16);
      *reinterpret_cast<ushort*>(qb + swz256(nb+2, 2*col)) = (ushort)u23;
      *reinterpret_cast<ushort*>(qb + swz256(nb+3, 2*col)) = (ushort)(u23 >> 16);
    }
  __syncthreads();   // (G)
  // ---- projection GEMM + output ----
  {
    const ushort* wp = wfrag + 3*16384;
    f32x4 acc[4];
    #pragma unroll
    for (int nt = 0; nt < 4; ++nt) acc[nt] = (f32x4){0.f,0.f,0.f,0.f};
    #pragma unroll
    for (int ks = 0; ks < 4; ++ks){
      const bf16x8 af = *reinterpret_cast<const bf16x8*>(qb + swz256(mt*16+c16, ks*64 + g*16));
      #pragma unroll
      for (int nt = 0; nt < 4; ++nt){
        const bf16x8 bf = *reinterpret_cast<const bf16x8*>(&wp[(((ntb+nt)*4 + ks)*64 + lane)*8]);
        acc[nt] = __builtin_amdgcn_mfma_f32_16x16x32_bf16(af, bf, acc[nt], 0, 0, 0);
      }
    }
    #pragma unroll
    for (int nt = 0; nt < 4; ++nt){
      const int co = (ntb+nt)*16 + c16;
      const float bias = pjb[co];
      #pragma unroll
      for (int r = 0; r < 4; ++r){
        const int n = n0 + r;
        out[(((long)t*H_ + (h0+(n>>3)))*W_ + (w0+(n&7)))*C_ + co] = acc[nt][r] + bias;
      }
    }
  }
}

extern "C" void kernel_launch(void* const* d_in, const int* in_sizes, int n_in,
                              void* d_out, int out_size, void* d_ws, size_t ws_size,
                              hipStream_t stream) {
  const float* vid  = (const float*)d_in[0];
  const float* rpb  = (const float*)d_in[1];
  const float* qdw  = (const float*)d_in[2];
  const float* qdwb = (const float*)d_in[3];
  const float* qpw  = (const float*)d_in[4];
  const float* qpwb = (const float*)d_in[5];
  const float* kdw  = (const float*)d_in[6];
  const float* kdwb = (const float*)d_in[7];
  const float* kpw  = (const float*)d_in[8];
  const float* kpwb = (const float*)d_in[9];
  const float* vdw  = (const float*)d_in[10];
  const float* vdwb = (const float*)d_in[11];
  const float* vpw  = (const float*)d_in[12];
  const float* vpwb = (const float*)d_in[13];
  const float* pjw  = (const float*)d_in[14];
  const float* pjb  = (const float*)d_in[15];
  float* outp = (float*)d_out;

  ushort* wfrag = (ushort*)((char*)d_ws + WS_WFRAG);
  float*  biasx = (float*)((char*)d_ws + WS_BIASX);

  prep_kernel<<<dim3(96), dim3(256), 0, stream>>>(qpw, kpw, vpw, pjw, rpb, wfrag, biasx);
  winattn_mfma3<<<dim3(NWIN_), dim3(512), 0, stream>>>(
      vid, qdw, qdwb, kdw, kdwb, vdw, vdwb, qpwb, kpwb, vpwb, pjb,
      wfrag, biasx, outp);
}

// Round 6
// 209.075 us; speedup vs baseline: 2.6846x; 2.6846x over previous
//
#include <hip/hip_runtime.h>
#include <hip/hip_fp16.h>
#include <stdint.h>

#define T_ 2
#define H_ 384
#define W_ 384
#define C_ 128
#define HN_ 48
#define WN_ 48
#define NWIN_ (T_*HN_*WN_)
#define SCALE_ 0.17677669529663687f

typedef float f32x4 __attribute__((ext_vector_type(4)));
typedef _Float16 f16x8 __attribute__((ext_vector_type(8)));

// ---- workspace ----
#define WS_WFRAG 0        // 4 mats x [nt8][ks][lane][8] f16 = 131072 B
#define WS_BIASX 131072   // [he][n][c16][m2] f32 = 65536 B
#define WS_DWF   196608   // [3][64 cp][12] half2-as-uint = 9216 B
#define WS_DWB   205824   // [3][64 cp] half2-as-uint = 768 B

// ---- LDS: 48 KB ----
// tmp[64 tok][256B f16]   (overlay: vt[128 d][128B])
// q  [64 tok][256B]       (overlay: P rows 0-127 [128B], O[64][256B])
// k  [64 tok][256B]       (overlay: P rows 128-255 [128B])
#define TMP_OFF 0
#define Q_OFF   16384
#define K_OFF   32768
#define SMEM_SZ 49152

__device__ __forceinline__ unsigned int pkh(float a, float b){
  union{__half2 h; unsigned int u;} c;
  c.h = __float22half2_rn(make_float2(a, b));
  return c.u;
}
__device__ __forceinline__ unsigned short f2h(float f){
  union{__half h; unsigned short u;} c; c.h = __float2half_rn(f); return c.u;
}
__device__ __forceinline__ __half2 u2h(unsigned int u){
  union{unsigned int u; __half2 h;} c; c.u = u; return c.h;
}
// packed-half ReLU via sign-mask (exact for non-NaN): lane<0 -> 0
__device__ __forceinline__ unsigned int relu2u(__half2 v){
  union{__half2 h; unsigned int u;} c; c.h = v;
  const unsigned int m = ((c.u >> 15) & 0x00010001u) * 0xFFFFu;
  return c.u & ~m;
}
__device__ __forceinline__ int swz256(int row, int b){ return row*256 + (b ^ ((row & 15) << 4)); }
__device__ __forceinline__ int swz128(int row, int b){ return row*128 + (b ^ ((row & 7) << 4)); }

// ---------- prep: all weights -> f16 (fragment order); rpb -> expanded bias; dw packed ----------
__global__ __launch_bounds__(256)
void prep_kernel(const float* __restrict__ qpw, const float* __restrict__ kpw,
                 const float* __restrict__ vpw, const float* __restrict__ pjw,
                 const float* __restrict__ rpb,
                 const float* __restrict__ qdw, const float* __restrict__ kdw,
                 const float* __restrict__ vdw,
                 const float* __restrict__ qdwb, const float* __restrict__ kdwb,
                 const float* __restrict__ vdwb,
                 ushort* __restrict__ wfrag, float* __restrict__ biasx,
                 unsigned int* __restrict__ dwf, unsigned int* __restrict__ dwb2)
{
  const int idx = blockIdx.x*256 + threadIdx.x;
  if (idx < 8192) {
    const int mat = idx >> 11, rem = idx & 2047;
    const int nt8 = rem >> 8, ks = (rem >> 6) & 3, lane = rem & 63;
    const int c16 = lane & 15, g = lane >> 4;
    const float* Ws[4] = {qpw, kpw, vpw, pjw};
    const float* src = Ws[mat] + (nt8*16 + c16)*128 + ks*32 + g*8;
    ushort* dst = wfrag + idx*8;
    #pragma unroll
    for (int e = 0; e < 8; ++e) dst[e] = f2h(src[e]);
  } else if (idx < 24576) {
    const int i2 = idx - 8192;
    const int he = i2 >> 12, n = (i2 >> 6) & 63, m = i2 & 63;
    const int ny = n >> 3, nx = n & 7, my = m >> 3, mx = m & 7;
    biasx[((he*64 + n)*16 + (m & 15))*4 + (m >> 4)] =
        rpb[((ny - my + 7)*15 + (nx - mx + 7))*4 + he];
  } else if (idx < 24576 + 2304) {
    const int i2 = idx - 24576;
    const int p = i2 / 768, rem = i2 % 768, cp = rem / 12, j = rem % 12;
    const float* dws[3] = {qdw, kdw, vdw};
    unsigned int v = 0;
    if (j < 9) v = pkh(dws[p][(2*cp)*9 + j], dws[p][(2*cp+1)*9 + j]);
    dwf[(p*64 + cp)*12 + j] = v;
  } else if (idx < 24576 + 2304 + 192) {
    const int i2 = idx - 24576 - 2304;
    const int p = i2 >> 6, cp = i2 & 63;
    const float* dbs[3] = {qdwb, kdwb, vdwb};
    dwb2[p*64 + cp] = pkh(dbs[p][2*cp], dbs[p][2*cp+1]);
  }
}

// ---------- main ----------
__global__ __launch_bounds__(512, 8)
void winattn_mfma4(const float* __restrict__ vid,
                   const float* __restrict__ qpwb, const float* __restrict__ kpwb,
                   const float* __restrict__ vpwb, const float* __restrict__ pjb,
                   const ushort* __restrict__ wfrag, const float* __restrict__ biasx,
                   const unsigned int* __restrict__ dwf, const unsigned int* __restrict__ dwb2,
                   float* __restrict__ out)
{
  __shared__ __attribute__((aligned(16))) char smem[SMEM_SZ];
  char* tmpb = smem + TMP_OFF;   // tmp (256B rows) / vt (128B rows)
  char* qb   = smem + Q_OFF;     // q / P rows 0-255 (spans q+k) / O
  char* kb   = smem + K_OFF;     // k

  const int tid  = threadIdx.x;
  const int w    = tid >> 6;
  const int lane = tid & 63;
  const int g    = lane >> 4;
  const int c16  = lane & 15;

  // XCD-aware bijective swizzle (4608 % 8 == 0)
  const int wid = (blockIdx.x & 7) * (NWIN_ / 8) + (blockIdx.x >> 3);
  const int t  = wid / (HN_*WN_);
  const int hw = wid % (HN_*WN_);
  const int hn = hw / WN_, wn = hw % WN_;
  const int h0 = hn*8, w0 = wn*8;

  // ---- input halo -> packed f16 registers (wave = row y, lane = channel pair) ----
  const int y = w;
  __half2 hx[3][10];
  #pragma unroll
  for (int dy = 0; dy < 3; ++dy){
    const int hh = h0 + y - 1 + dy;
    const bool rv = (unsigned)hh < (unsigned)H_;
    #pragma unroll
    for (int xc = 0; xc < 10; ++xc){
      const int ww = w0 - 1 + xc;
      float2 l = make_float2(0.f, 0.f);
      if (rv && (unsigned)ww < (unsigned)W_)
        l = *reinterpret_cast<const float2*>(&vid[(((long)t*H_ + hh)*W_ + ww)*C_ + 2*lane]);
      hx[dy][xc] = __float22half2_rn(l);
    }
  }

  const int mt  = w & 3;
  const int ntb = (w >> 2) * 4;
  const int n0  = mt*16 + g*4;

  #pragma unroll
  for (int p = 0; p < 3; ++p) {
    // ---- depthwise 3x3 + bias + relu, packed f16 (v_pk_fma_f16) ----
    {
      const uint4* dq = reinterpret_cast<const uint4*>(dwf + (p*64 + lane)*12);
      const uint4 wA = dq[0], wB = dq[1], wC = dq[2];
      const __half2 w9[9] = { u2h(wA.x), u2h(wA.y), u2h(wA.z), u2h(wA.w),
                              u2h(wB.x), u2h(wB.y), u2h(wB.z), u2h(wB.w), u2h(wC.x) };
      const __half2 b2 = u2h(dwb2[p*64 + lane]);
      __half2 acc[8];
      #pragma unroll
      for (int px = 0; px < 8; ++px) acc[px] = b2;
      #pragma unroll
      for (int dy = 0; dy < 3; ++dy)
        #pragma unroll
        for (int dx = 0; dx < 3; ++dx){
          const __half2 w2 = w9[dy*3+dx];
          #pragma unroll
          for (int px = 0; px < 8; ++px)
            acc[px] = __hfma2(hx[dy][px+dx], w2, acc[px]);
        }
      #pragma unroll
      for (int px = 0; px < 8; ++px)
        *reinterpret_cast<unsigned int*>(tmpb + swz256(y*8+px, 4*lane)) = relu2u(acc[px]);
    }
    __syncthreads();
    // ---- pointwise GEMM: Y[64,128] = X @ W^T (B-frags from L2), nt-split halves ----
    const ushort* wp = wfrag + p*16384;
    const float scl = (p == 0) ? SCALE_ : 1.0f;
    if (p < 2) {
      char* dst = (p == 0) ? qb : kb;
      const float* pwb = (p == 0) ? qpwb : kpwb;
      #pragma unroll
      for (int nh = 0; nh < 2; ++nh){
        f32x4 a2[2] = {{0.f,0.f,0.f,0.f},{0.f,0.f,0.f,0.f}};
        #pragma unroll
        for (int ks = 0; ks < 4; ++ks){
          const f16x8 af = *reinterpret_cast<const f16x8*>(tmpb + swz256(mt*16+c16, ks*64 + g*16));
          #pragma unroll
          for (int j = 0; j < 2; ++j){
            const f16x8 bf = *reinterpret_cast<const f16x8*>(&wp[(((ntb+nh*2+j)*4 + ks)*64 + lane)*8]);
            a2[j] = __builtin_amdgcn_mfma_f32_16x16x32_f16(af, bf, a2[j], 0, 0, 0);
          }
        }
        #pragma unroll
        for (int j = 0; j < 2; ++j){
          const int co = (ntb+nh*2+j)*16 + c16;
          const float bias = pwb[co];
          const unsigned int u01 = pkh((a2[j][0]+bias)*scl, (a2[j][1]+bias)*scl);
          const unsigned int u23 = pkh((a2[j][2]+bias)*scl, (a2[j][3]+bias)*scl);
          *reinterpret_cast<ushort*>(dst + swz256(n0+0, 2*co)) = (ushort)u01;
          *reinterpret_cast<ushort*>(dst + swz256(n0+1, 2*co)) = (ushort)(u01 >> 16);
          *reinterpret_cast<ushort*>(dst + swz256(n0+2, 2*co)) = (ushort)u23;
          *reinterpret_cast<ushort*>(dst + swz256(n0+3, 2*co)) = (ushort)(u23 >> 16);
        }
      }
      __syncthreads();   // tmp reads done -> next p overwrites tmp
    } else {
      uint2 vtr[4];
      #pragma unroll
      for (int nh = 0; nh < 2; ++nh){
        f32x4 a2[2] = {{0.f,0.f,0.f,0.f},{0.f,0.f,0.f,0.f}};
        #pragma unroll
        for (int ks = 0; ks < 4; ++ks){
          const f16x8 af = *reinterpret_cast<const f16x8*>(tmpb + swz256(mt*16+c16, ks*64 + g*16));
          #pragma unroll
          for (int j = 0; j < 2; ++j){
            const f16x8 bf = *reinterpret_cast<const f16x8*>(&wp[(((ntb+nh*2+j)*4 + ks)*64 + lane)*8]);
            a2[j] = __builtin_amdgcn_mfma_f32_16x16x32_f16(af, bf, a2[j], 0, 0, 0);
          }
        }
        #pragma unroll
        for (int j = 0; j < 2; ++j){
          const float bias = vpwb[(ntb+nh*2+j)*16 + c16];
          vtr[nh*2+j] = make_uint2(pkh(a2[j][0]+bias, a2[j][1]+bias),
                                   pkh(a2[j][2]+bias, a2[j][3]+bias));
        }
      }
      __syncthreads();   // (C) all tmp reads done -> overlay V^T onto tmp
      #pragma unroll
      for (int nt = 0; nt < 4; ++nt)
        *reinterpret_cast<uint2*>(tmpb + swz128((ntb+nt)*16 + c16, 2*n0)) = vtr[nt];
    }
  }

  // ---- attention: wave (he, half) owns 32 query rows of head he ----
  const int he = w >> 1, half = w & 1;
  unsigned int pu[2][4][2];   // packed normalized P (f16 pairs)
  {
    f32x4 S[2][4];
    #pragma unroll
    for (int mi = 0; mi < 2; ++mi){
      const f16x8 qf = *reinterpret_cast<const f16x8*>(qb + swz256((half*2+mi)*16 + c16, he*64 + g*16));
      #pragma unroll
      for (int m2 = 0; m2 < 4; ++m2){
        const f16x8 kf = *reinterpret_cast<const f16x8*>(kb + swz256(m2*16 + c16, he*64 + g*16));
        const f32x4 z = {0.f,0.f,0.f,0.f};
        S[mi][m2] = __builtin_amdgcn_mfma_f32_16x16x32_f16(qf, kf, z, 0, 0, 0);
      }
    }
    #pragma unroll
    for (int mi = 0; mi < 2; ++mi){
      #pragma unroll
      for (int r = 0; r < 4; ++r){
        const int n = (half*2+mi)*16 + g*4 + r;
        const float4 bx = *reinterpret_cast<const float4*>(&biasx[((he*64+n)*16 + c16)*4]);
        float v0 = S[mi][0][r]+bx.x, v1 = S[mi][1][r]+bx.y;
        float v2 = S[mi][2][r]+bx.z, v3 = S[mi][3][r]+bx.w;
        float mx = fmaxf(fmaxf(v0,v1), fmaxf(v2,v3));
        mx = fmaxf(mx, __shfl_xor(mx, 1));
        mx = fmaxf(mx, __shfl_xor(mx, 2));
        mx = fmaxf(mx, __shfl_xor(mx, 4));
        mx = fmaxf(mx, __shfl_xor(mx, 8));
        const float e0 = __expf(v0-mx), e1 = __expf(v1-mx);
        const float e2 = __expf(v2-mx), e3 = __expf(v3-mx);
        float ls = e0+e1+e2+e3;
        ls += __shfl_xor(ls, 1);
        ls += __shfl_xor(ls, 2);
        ls += __shfl_xor(ls, 4);
        ls += __shfl_xor(ls, 8);
        const float inv = 1.0f / ls;
        pu[mi][r][0] = pkh(e0*inv, e1*inv);
        pu[mi][r][1] = pkh(e2*inv, e3*inv);
      }
    }
  }
  __syncthreads();   // (D) V^T writes done; q/k reads done -> P may overlay q+k
  #pragma unroll
  for (int mi = 0; mi < 2; ++mi)
    #pragma unroll
    for (int r = 0; r < 4; ++r){
      const int rr = he*64 + (half*2+mi)*16 + g*4 + r;
      *reinterpret_cast<ushort*>(qb + swz128(rr,  0 + 2*c16)) = (ushort)pu[mi][r][0];
      *reinterpret_cast<ushort*>(qb + swz128(rr, 32 + 2*c16)) = (ushort)(pu[mi][r][0] >> 16);
      *reinterpret_cast<ushort*>(qb + swz128(rr, 64 + 2*c16)) = (ushort)pu[mi][r][1];
      *reinterpret_cast<ushort*>(qb + swz128(rr, 96 + 2*c16)) = (ushort)(pu[mi][r][1] >> 16);
    }
  __syncthreads();   // (E)
  // ---- PV: O = P @ V (A=P overlay, B=V^T in tmp) ----
  {
    f32x4 oacc[2][2];
    #pragma unroll
    for (int mi = 0; mi < 2; ++mi)
      #pragma unroll
      for (int nt = 0; nt < 2; ++nt) oacc[mi][nt] = (f32x4){0.f,0.f,0.f,0.f};
    #pragma unroll
    for (int ks = 0; ks < 2; ++ks){
      #pragma unroll
      for (int nt = 0; nt < 2; ++nt){
        const f16x8 vf = *reinterpret_cast<const f16x8*>(tmpb + swz128(he*32+nt*16+c16, ks*64 + g*16));
        #pragma unroll
        for (int mi = 0; mi < 2; ++mi){
          const f16x8 pf = *reinterpret_cast<const f16x8*>(qb + swz128(he*64+(half*2+mi)*16+c16, ks*64 + g*16));
          oacc[mi][nt] = __builtin_amdgcn_mfma_f32_16x16x32_f16(pf, vf, oacc[mi][nt], 0, 0, 0);
        }
      }
    }
    __syncthreads();   // (F) P reads done -> O may overwrite q region
    #pragma unroll
    for (int mi = 0; mi < 2; ++mi)
      #pragma unroll
      for (int nt = 0; nt < 2; ++nt){
        const int col = he*32 + nt*16 + c16;
        const int nb = (half*2+mi)*16 + g*4;
        const unsigned int u01 = pkh(oacc[mi][nt][0], oacc[mi][nt][1]);
        const unsigned int u23 = pkh(oacc[mi][nt][2], oacc[mi][nt][3]);
        *reinterpret_cast<ushort*>(qb + swz256(nb+0, 2*col)) = (ushort)u01;
        *reinterpret_cast<ushort*>(qb + swz256(nb+1, 2*col)) = (ushort)(u01 >> 16);
        *reinterpret_cast<ushort*>(qb + swz256(nb+2, 2*col)) = (ushort)u23;
        *reinterpret_cast<ushort*>(qb + swz256(nb+3, 2*col)) = (ushort)(u23 >> 16);
      }
  }
  __syncthreads();   // (G)
  // ---- projection GEMM + output (nt-split halves) ----
  {
    const ushort* wp = wfrag + 3*16384;
    #pragma unroll
    for (int nh = 0; nh < 2; ++nh){
      f32x4 a2[2] = {{0.f,0.f,0.f,0.f},{0.f,0.f,0.f,0.f}};
      #pragma unroll
      for (int ks = 0; ks < 4; ++ks){
        const f16x8 af = *reinterpret_cast<const f16x8*>(qb + swz256(mt*16+c16, ks*64 + g*16));
        #pragma unroll
        for (int j = 0; j < 2; ++j){
          const f16x8 bf = *reinterpret_cast<const f16x8*>(&wp[(((ntb+nh*2+j)*4 + ks)*64 + lane)*8]);
          a2[j] = __builtin_amdgcn_mfma_f32_16x16x32_f16(af, bf, a2[j], 0, 0, 0);
        }
      }
      #pragma unroll
      for (int j = 0; j < 2; ++j){
        const int co = (ntb+nh*2+j)*16 + c16;
        const float bias = pjb[co];
        #pragma unroll
        for (int r = 0; r < 4; ++r){
          const int n = n0 + r;
          out[(((long)t*H_ + (h0+(n>>3)))*W_ + (w0+(n&7)))*C_ + co] = a2[j][r] + bias;
        }
      }
    }
  }
}

extern "C" void kernel_launch(void* const* d_in, const int* in_sizes, int n_in,
                              void* d_out, int out_size, void* d_ws, size_t ws_size,
                              hipStream_t stream) {
  const float* vid  = (const float*)d_in[0];
  const float* rpb  = (const float*)d_in[1];
  const float* qdw  = (const float*)d_in[2];
  const float* qdwb = (const float*)d_in[3];
  const float* qpw  = (const float*)d_in[4];
  const float* qpwb = (const float*)d_in[5];
  const float* kdw  = (const float*)d_in[6];
  const float* kdwb = (const float*)d_in[7];
  const float* kpw  = (const float*)d_in[8];
  const float* kpwb = (const float*)d_in[9];
  const float* vdw  = (const float*)d_in[10];
  const float* vdwb = (const float*)d_in[11];
  const float* vpw  = (const float*)d_in[12];
  const float* vpwb = (const float*)d_in[13];
  const float* pjw  = (const float*)d_in[14];
  const float* pjb  = (const float*)d_in[15];
  float* outp = (float*)d_out;

  ushort*       wfrag = (ushort*)((char*)d_ws + WS_WFRAG);
  float*        biasx = (float*)((char*)d_ws + WS_BIASX);
  unsigned int* dwf   = (unsigned int*)((char*)d_ws + WS_DWF);
  unsigned int* dwb2  = (unsigned int*)((char*)d_ws + WS_DWB);

  prep_kernel<<<dim3(106), dim3(256), 0, stream>>>(
      qpw, kpw, vpw, pjw, rpb, qdw, kdw, vdw, qdwb, kdwb, vdwb,
      wfrag, biasx, dwf, dwb2);
  winattn_mfma4<<<dim3(NWIN_), dim3(512), 0, stream>>>(
      vid, qpwb, kpwb, vpwb, pjb, wfrag, biasx, dwf, dwb2, outp);
}